// Round 7
// baseline (220.608 us; speedup 1.0000x reference)
//
#include <hip/hip_runtime.h>
#include <hip/hip_bf16.h>
#include <math.h>

#define BATCH 8
#define NPTS 4096
#define CH 128
#define NTILEBLOCKS (32 * 16 * BATCH)   // tile_kernel grid size

// exp(s/TEMP) = 2^(s * 10 * log2(e)). sqrt(10/ln2) is folded into the
// normalize scale so the GEMM accumulator is already the exp2 argument.
#define SQRT_TEMP_LOG2E 3.79828256f   // sqrt(14.4269504089)

typedef __attribute__((ext_vector_type(16))) float f32x16;
typedef __attribute__((ext_vector_type(4)))  int   i32x4;
typedef __attribute__((ext_vector_type(8)))  short bf16x8;

typedef __attribute__((address_space(3))) unsigned int lds_uint;
typedef __attribute__((address_space(1))) const unsigned int gbl_uint;

__device__ __forceinline__ void load_lds16(const void* g, const void* l) {
    __builtin_amdgcn_global_load_lds((gbl_uint*)g, (lds_uint*)l, 16, 0, 0);
}

// v_exp_f32 is 2^x. (__exp2f collides with a glibc math.h macro.)
__device__ __forceinline__ float fast_exp2(float x) {
    return __builtin_amdgcn_exp2f(x);
}

// ---------------------------------------------------------------------------
// Kernel 1: one-pass L2-normalize (4 threads/point, 32 ch each in registers),
// zero pos/neg and the completion counter.
// ---------------------------------------------------------------------------
__global__ __launch_bounds__(256) void normalize_kernel(
    const float* __restrict__ f, __hip_bfloat16* __restrict__ vn,
    float* __restrict__ pos, float* __restrict__ neg, int* __restrict__ counter)
{
    int idx = blockIdx.x * 256 + threadIdx.x;   // 0 .. 131071
    int point = idx >> 2, q = idx & 3;
    int b = point >> 12, n = point & (NPTS - 1);
    const float* base = f + (size_t)b * CH * NPTS + (size_t)(q * 32) * NPTS + n;

    float x[32];
    float ss = 0.0f;
    #pragma unroll
    for (int c = 0; c < 32; c++) {
        x[c] = base[(size_t)c * NPTS];
        ss += x[c] * x[c];
    }
    ss += __shfl_xor(ss, 1);
    ss += __shfl_xor(ss, 2);    // 4 lanes of one point share ss
    float scale = SQRT_TEMP_LOG2E / fmaxf(sqrtf(ss), 1e-12f);

    __hip_bfloat16* out = vn + (size_t)point * CH + q * 32;
    #pragma unroll
    for (int c0 = 0; c0 < 32; c0 += 8) {
        union { __hip_bfloat16 h[8]; uint4 u; } pk;
        #pragma unroll
        for (int j = 0; j < 8; j++)
            pk.h[j] = __float2bfloat16(x[c0 + j] * scale);
        *((uint4*)(out + c0)) = pk.u;
    }
    if (q == 0) pos[point] = 0.0f;
    else if (q == 1) neg[point] = 0.0f;
    if (idx == 0) *counter = 0;
}

// ---------------------------------------------------------------------------
// Kernel 2: 256x128 block tile, 32x32x16 MFMA with SWAPPED operands.
//
// R6 post-mortem: 16x16x32 structure was LDS-BW bound (32 ds_read_b128 per
// 32 MFMAs per wave; 8 MB LDS reads/CU ~= 40 us ~= measured dur). 32x32x16
// moves 2x the FLOP per 1 KB B-fragment: wave owns 32 rows x 128 cols ->
// per-CU LDS reads halve to 4 MB (~20 us floor).
//
// Swapped operands (R6-verified trick, same operand-layout symmetry):
// mfma(bfrag, afrag, acc) puts S-row on lane&31 and S-col on
// (reg&3)+8*(reg>>2)+4*(lane>>5) within the 32-col block -> pos/total
// reductions stay in-lane; single shfl_xor(32) fold + 2 atomics/row.
//
// Fused finalize: device-scope completion counter; the last of the 4096
// blocks volatile-reads pos/neg (all prior atomics drained by each block's
// __syncthreads + threadfence before its counter bump) and writes out.
//
// launch_bounds(512,4): 128-VGPR cap (acc 64 + afrag 32 + misc; R4 showed
// an 85-cap spills catastrophically — do not tighten).
// ---------------------------------------------------------------------------
__global__ __launch_bounds__(512, 4) void tile_kernel(
    const __hip_bfloat16* __restrict__ vn, const int* __restrict__ labels,
    float* __restrict__ pos, float* __restrict__ neg,
    int* __restrict__ counter, float* __restrict__ out)
{
    __shared__ short lB[128 * CH];   // 32 KB: B-tile (128 cols of S)
    __shared__ int labC[128];
    __shared__ int lastFlag;
    __shared__ float red[8];

    const int b   = blockIdx.z;
    const int ct  = blockIdx.x;           // col tile (128 wide)
    const int row0 = blockIdx.y * 256;    // 256-row block tile
    const int col0 = ct * 128;

    const int tid = threadIdx.x;
    const int w = tid >> 6, lane = tid & 63;
    const int lane31 = lane & 31, lane15 = lane & 15;
    const int quad = (lane >> 4) & 3, h = lane >> 5;

    const __hip_bfloat16* vb = vn + (size_t)b * NPTS * CH;

    if (tid < 128) labC[tid] = labels[b * NPTS + col0 + tid];

    // Stage B-tile -> LDS via global_load_lds, XOR chunk swizzle at the
    // global source (LDS dest order is HW-fixed: wave-uniform base +
    // lane*16B). R1..R6: SQ_LDS_BANK_CONFLICT == 0 with this scheme.
    {
        const __hip_bfloat16* Bb = vb + (size_t)col0 * CH;
        #pragma unroll
        for (int i = 0; i < 4; i++) {
            int rsw = (i * 4 + quad) & 15;
            int g   = lane15 ^ rsw;
            int row = w * 16 + i * 4 + quad;
            int ldsrow = w * 16 + i * 4;          // wave-uniform
            load_lds16(Bb + (size_t)row * CH + g * 8, &lB[ldsrow * CH]);
        }
    }

    // A-fragments direct from global: row = row0 + w*32 + lane31,
    // k-chunk (16B) index 2*ks + h. Latency hidden by the barrier drain.
    const int rowl = w * 32 + lane31;             // local S-row (0..255)
    bf16x8 afrag[8];
    {
        const __hip_bfloat16* Arow = vb + (size_t)(row0 + rowl) * CH + h * 8;
        #pragma unroll
        for (int ks = 0; ks < 8; ks++)
            afrag[ks] = *(const bf16x8*)(Arow + ks * 16);
    }
    const int lr = labels[b * NPTS + row0 + rowl];

    __syncthreads();   // drains vmcnt (incl. global_load_lds)

    // MFMA: acc[nb] holds S[row0+rowl][col0 + nb*32 + coff(reg,h)].
    f32x16 acc[4] = {};
    #pragma unroll
    for (int ks = 0; ks < 8; ks++) {
        const int koff = ((2 * ks + h) ^ lane15) << 3;   // swizzled, shorts
        #pragma unroll
        for (int nb = 0; nb < 4; nb++) {
            bf16x8 bf = *(const bf16x8*)&lB[(nb * 32 + lane31) * CH + koff];
            acc[nb] = __builtin_amdgcn_mfma_f32_32x32x16_bf16(
                bf, afrag[ks], acc[nb], 0, 0, 0);
        }
    }

    // Epilogue: in-lane over 64 elements; col offset = g*8 + 4*h + r.
    float p = 0.0f, tt = 0.0f;
    #pragma unroll
    for (int nb = 0; nb < 4; nb++) {
        if (row0 + w * 32 == col0 + nb * 32) {    // wave-uniform diag block
            #pragma unroll
            for (int g = 0; g < 4; g++) {
                const i32x4 lc = *(const i32x4*)&labC[nb * 32 + g * 8 + 4 * h];
                #pragma unroll
                for (int r = 0; r < 4; r++) {
                    float e = fast_exp2(acc[nb][g * 4 + r]);
                    if (lane31 == g * 8 + 4 * h + r) e = 0.0f;  // diagonal
                    tt += e;
                    p  += (lc[r] == lr) ? e : 0.0f;
                }
            }
        } else {
            #pragma unroll
            for (int g = 0; g < 4; g++) {
                const i32x4 lc = *(const i32x4*)&labC[nb * 32 + g * 8 + 4 * h];
                #pragma unroll
                for (int r = 0; r < 4; r++) {
                    float e = fast_exp2(acc[nb][g * 4 + r]);
                    tt += e;
                    p  += (lc[r] == lr) ? e : 0.0f;
                }
            }
        }
    }

    // Fold the two half-wave copies of each S-row, then 2 atomics per row.
    p  += __shfl_xor(p, 32);
    tt += __shfl_xor(tt, 32);
    if (lane < 32) {
        atomicAdd(&pos[b * NPTS + row0 + rowl], p);
        atomicAdd(&neg[b * NPTS + row0 + rowl], tt - p);
    }

    // --- Fused finalize: last block reduces log((p+n)/p) and writes out. ---
    __syncthreads();                 // all waves' atomics drained (vmcnt 0)
    if (tid == 0) {
        __threadfence();             // order our atomics before the bump
        int c = atomicAdd(counter, 1);
        lastFlag = (c == NTILEBLOCKS - 1);
    }
    __syncthreads();
    if (lastFlag) {
        __threadfence();
        volatile const float* vp = pos;
        volatile const float* vq = neg;
        float acc2 = 0.0f;
        for (int i = tid; i < BATCH * NPTS; i += 512) {
            float pp = vp[i], qq = vq[i];
            acc2 += __logf((pp + qq) / pp);    // == -log(p/(p+n))
        }
        #pragma unroll
        for (int off = 32; off; off >>= 1) acc2 += __shfl_down(acc2, off);
        if (lane == 0) red[w] = acc2;
        __syncthreads();
        if (tid < 8) {
            float v = red[tid];
            #pragma unroll
            for (int off = 4; off; off >>= 1) v += __shfl_down(v, off);
            if (tid == 0) out[0] = v * (1.0f / (BATCH * NPTS));
        }
    }
}

extern "C" void kernel_launch(void* const* d_in, const int* in_sizes, int n_in,
                              void* d_out, int out_size, void* d_ws, size_t ws_size,
                              hipStream_t stream)
{
    const float* features = (const float*)d_in[0];
    const int*   labels   = (const int*)d_in[1];
    float*       out      = (float*)d_out;

    // Workspace: vn bf16 [8][4096][128] = 8 MB, pos/neg fp32, counter.
    __hip_bfloat16* vn = (__hip_bfloat16*)d_ws;
    float* pos = (float*)((char*)d_ws + (size_t)BATCH * NPTS * CH * sizeof(__hip_bfloat16));
    float* neg = pos + BATCH * NPTS;
    int* counter = (int*)(neg + BATCH * NPTS);

    hipLaunchKernelGGL(normalize_kernel, dim3(BATCH * NPTS * 4 / 256), dim3(256), 0, stream,
                       features, vn, pos, neg, counter);
    // 32 col-tiles x 16 row-tiles (256 rows) x 8 batches = 4096 blocks.
    hipLaunchKernelGGL(tile_kernel, dim3(32, 16, BATCH), dim3(512), 0, stream,
                       vn, labels, pos, neg, counter, out);
}